// Round 13
// baseline (40.533 us; speedup 1.0000x reference)
//
#include <hip/hip_runtime.h>
#include <hip/hip_bf16.h>

// Problem constants (B=4, T=4096, C=2048, E=64)
#define N_TOK   16384
#define C_DIM   2048
#define E_DIM   64
#define P_OFF   (N_TOK * E_DIM)        // 1048576 — end of probs section
#define FB_OFF  P_OFF                  // fallback_count scalar
#define LG_OFF  (P_OFF + 1)            // logits section
#define AM_OFF  (2 * P_OFF + 1)        // activation_mask section

typedef __attribute__((ext_vector_type(8))) short bf16x8;  // 8 bf16 in 4 VGPRs
typedef __attribute__((ext_vector_type(4))) float f32x4;

static __device__ __forceinline__ unsigned short f2bf_rtn(float f) {
    unsigned u = __float_as_uint(f);
    unsigned r = u + 0x7FFFu + ((u >> 16) & 1u);   // round-to-nearest-even
    return (unsigned short)(r >> 16);
}
static __device__ __forceinline__ float bf2f(unsigned short h) {
    return __uint_as_float(((unsigned)h) << 16);
}
static __device__ __forceinline__ short f2bf_hw(float f) {
    __hip_bfloat16 h = __float2bfloat16(f);   // HW cvt; pairs fuse to v_cvt_pk_bf16_f32
    return *reinterpret_cast<short*>(&h);
}

// ---------------------------------------------------------------------------
// Kernel 1: prepack sim_matrix [2048,64] f32 -> bf16 (RTN) MFMA fragments.
// kk-step it (32 k): layout [it(64)][nb(4)][lane(64)][i(8)] shorts (256 KB).
// Content: lane l, elem i -> sim[it*32 + (l>>4)*8 + i][nb*16 + (l&15)]
// Also zero-initializes the fallback counter in d_out.
// ---------------------------------------------------------------------------
__global__ void gating_prepack(const float* __restrict__ sim,
                               unsigned short* __restrict__ Bpk,
                               float* __restrict__ out) {
    int tid = blockIdx.x * 256 + threadIdx.x;
    if (tid == 0) out[FB_OFF] = 0.0f;
    if (tid >= C_DIM * E_DIM) return;
    int k = tid >> 6;
    int e = tid & 63;
    float v = sim[tid];                       // sim[k*64 + e]
    int it = k >> 5;                          // kk-step 0..63
    int gr = (k >> 3) & 3;
    int i  = k & 7;
    int lane = gr * 16 + (e & 15);
    int nb   = e >> 4;
    Bpk[it * 2048 + nb * 512 + lane * 8 + i] = f2bf_rtn(v);
}

// ---------------------------------------------------------------------------
// Kernel 2 (R13): B-amortized mono GEMM + gating epilogue.
//
// Ledger through R12: scheduling neutral (x7), occupancy>16w/CU neutral,
// coalescing neutral; ONLY traffic cuts moved the number. Aggregate traffic
// 414 MB in ~33 us = 12.5 TB/s (subsystem-bound). Biggest remaining slice:
// B re-reads (268 MB: every 16-token block re-read all 256 KB of B).
//
// Geometry: grid 256 x 1024 thr (16 waves) = 1 block/CU, 16 waves/CU (the
// proven-sufficient concurrency). Block = 64 tokens; wave w = K-sixteenth
// (4 kk-steps of 32). Per kk-step: 4 B-fragments loaded ONCE, reused across
// 4 row-groups (16 MFMA / 4 B-loads). B traffic 268 -> 67 MB.
// Cross-wave K-reduction via bf16 LDS red[16][64][66] (132 KB, +2-short pad
// breaks pow2 bank stride; bf16 partial error ~0.2 << 4.88 threshold).
// Epilogue: 1024 lanes x 1 token x 4 experts (4x more parallel than before).
// ---------------------------------------------------------------------------
__global__ __launch_bounds__(1024, 4)
void gating_main(const float* __restrict__ x,
                 const unsigned short* __restrict__ Bpk,
                 const float* __restrict__ gates,
                 float* __restrict__ out) {
    __shared__ unsigned short red[16][64][66];   // 132 KB bf16 partials

    const int tid = threadIdx.x;
    const int l   = tid & 63;
    const int w   = tid >> 6;          // wave id 0..15 == K-sixteenth
    const int row0 = blockIdx.x * 64;
    const int g    = l >> 4;           // k-slot group (gemm) / token sub (epi)
    const int e0   = l & 15;

    // A: lane's base row (row-group rg adds rg*16 rows); wave's K-range
    const float* xbase = x + (size_t)(row0 + e0) * C_DIM + w * 128 + g * 8;
    // B: kk-step it = w*4 + s; per-step stride 2048 shorts; lane frag base
    const unsigned short* bw = Bpk + (size_t)w * 4 * 2048 + l * 8;

    f32x4 acc[4][4];   // [rg][nb] = 64 VGPR
#pragma unroll
    for (int rg = 0; rg < 4; ++rg)
#pragma unroll
        for (int nb = 0; nb < 4; ++nb) acc[rg][nb] = (f32x4)0.0f;

    // ---- K loop: 4 kk-steps; B loaded once per step, reused 4x ----
    for (int s = 0; s < 4; ++s) {
        const unsigned short* bs = bw + s * 2048;
        bf16x8 bf[4];
#pragma unroll
        for (int nb = 0; nb < 4; ++nb)
            bf[nb] = *(const bf16x8*)(bs + nb * 512);

#pragma unroll
        for (int rg = 0; rg < 4; ++rg) {
            const float* ap = xbase + (size_t)rg * 16 * C_DIM + s * 32;
            float4 a0 = *(const float4*)ap;
            float4 a1 = *(const float4*)(ap + 4);
            bf16x8 ah;
            ah[0] = f2bf_hw(a0.x); ah[1] = f2bf_hw(a0.y);
            ah[2] = f2bf_hw(a0.z); ah[3] = f2bf_hw(a0.w);
            ah[4] = f2bf_hw(a1.x); ah[5] = f2bf_hw(a1.y);
            ah[6] = f2bf_hw(a1.z); ah[7] = f2bf_hw(a1.w);
#pragma unroll
            for (int nb = 0; nb < 4; ++nb)
                acc[rg][nb] = __builtin_amdgcn_mfma_f32_16x16x32_bf16(ah, bf[nb], acc[rg][nb], 0, 0, 0);
        }
    }

    // ---- write bf16 partials: C/D row = g*4 + r within 16-token group rg ----
#pragma unroll
    for (int rg = 0; rg < 4; ++rg)
#pragma unroll
        for (int nb = 0; nb < 4; ++nb)
#pragma unroll
            for (int r = 0; r < 4; ++r)
                red[w][rg * 16 + g * 4 + r][nb * 16 + e0] = f2bf_rtn(acc[rg][nb][r]);
    __syncthreads();

    // ---- epilogue: lane handles token tloc = w*4 + g, experts nb*16+e0 ----
    const int tloc = w * 4 + g;        // 0..63
    const int t    = row0 + tloc;

    float tot[4];
#pragma unroll
    for (int nb = 0; nb < 4; ++nb) {
        float t0 = 0.0f;
#pragma unroll
        for (int s = 0; s < 16; ++s)
            t0 += bf2f(red[s][tloc][nb * 16 + e0]);
        tot[nb] = t0;
    }

    float sig[4];
#pragma unroll
    for (int nb = 0; nb < 4; ++nb)
        sig[nb] = 1.0f / (1.0f + expf(-gates[nb * 16 + e0]));

    float lg[4];
    bool  act[4];
    int   lcnt = 0;
    float lmax = -3.4e38f;
#pragma unroll
    for (int nb = 0; nb < 4; ++nb) {
        lg[nb]  = tot[nb] - sig[nb];
        act[nb] = lg[nb] > 0.0f;
        if (act[nb]) { lcnt++; lmax = fmaxf(lmax, lg[nb]); }
    }
    int cnt = lcnt;
    float mx = lmax;
#pragma unroll
    for (int m = 1; m < 16; m <<= 1) {
        cnt += __shfl_xor(cnt, m, 16);
        mx   = fmaxf(mx, __shfl_xor(mx, m, 16));
    }

    float p[4], am[4];
    if (cnt > 0) {
        float ex[4], ls = 0.0f;
#pragma unroll
        for (int nb = 0; nb < 4; ++nb) {
            ex[nb] = act[nb] ? expf(lg[nb] - mx) : 0.0f;
            ls += ex[nb];
        }
        float Z = ls;
#pragma unroll
        for (int m = 1; m < 16; m <<= 1) Z += __shfl_xor(Z, m, 16);
        float rz = 1.0f / Z;
#pragma unroll
        for (int nb = 0; nb < 4; ++nb) {
            p[nb]  = ex[nb] * rz;
            am[nb] = act[nb] ? 1.0f : 0.0f;
        }
    } else {
        // fallback: top-32 of the 64 logits (ties -> lower expert index).
        // All logits <= 0 here, so probs are uniform 1/32 over the set.
        unsigned selm = 0;
        for (int it = 0; it < 32; ++it) {
            float bv = -3.4e38f;
            int   bi = 127;
#pragma unroll
            for (int nb = 0; nb < 4; ++nb) {
                if (!((selm >> nb) & 1)) {
                    float v = lg[nb];
                    int   e = nb * 16 + e0;
                    if (v > bv || (v == bv && e < bi)) { bv = v; bi = e; }
                }
            }
#pragma unroll
            for (int m = 1; m < 16; m <<= 1) {
                float ov = __shfl_xor(bv, m, 16);
                int   oi = __shfl_xor(bi, m, 16);
                if (ov > bv || (ov == bv && oi < bi)) { bv = ov; bi = oi; }
            }
            if ((bi & 15) == e0) selm |= 1u << (bi >> 4);
        }
#pragma unroll
        for (int nb = 0; nb < 4; ++nb) {
            bool s_ = (selm >> nb) & 1;
            p[nb]  = s_ ? (1.0f / 32.0f) : 0.0f;
            am[nb] = s_ ? 1.0f : 0.0f;
        }
        if (e0 == 0) atomicAdd(&out[FB_OFF], 1.0f);
    }

#pragma unroll
    for (int nb = 0; nb < 4; ++nb) {
        int idx = t * 64 + nb * 16 + e0;
        out[idx]          = p[nb];
        out[LG_OFF + idx] = lg[nb];
        out[AM_OFF + idx] = am[nb];
    }
}

// ---------------------------------------------------------------------------
extern "C" void kernel_launch(void* const* d_in, const int* in_sizes, int n_in,
                              void* d_out, int out_size, void* d_ws, size_t ws_size,
                              hipStream_t stream) {
    const float* x     = (const float*)d_in[0];   // [4,4096,2048] f32
    const float* sim   = (const float*)d_in[1];   // [2048,64] f32
    const float* gates = (const float*)d_in[2];   // [64] f32
    float* out = (float*)d_out;
    unsigned short* Bpk = (unsigned short*)d_ws;  // 256 KB prepacked B (bf16)

    gating_prepack<<<512, 256, 0, stream>>>(sim, Bpk, out);
    gating_main<<<256, 1024, 0, stream>>>(x, Bpk, gates, out);
}

// Round 14
// 36.118 us; speedup vs baseline: 1.1222x; 1.1222x over previous
//
#include <hip/hip_runtime.h>
#include <hip/hip_bf16.h>

// Problem constants (B=4, T=4096, C=2048, E=64)
#define N_TOK   16384
#define C_DIM   2048
#define E_DIM   64
#define P_OFF   (N_TOK * E_DIM)        // 1048576 — end of probs section
#define FB_OFF  P_OFF                  // fallback_count scalar
#define LG_OFF  (P_OFF + 1)            // logits section
#define AM_OFF  (2 * P_OFF + 1)        // activation_mask section

typedef __attribute__((ext_vector_type(8))) short bf16x8;  // 8 bf16 in 4 VGPRs
typedef __attribute__((ext_vector_type(4))) float f32x4;

static __device__ __forceinline__ unsigned short f2bf_rtn(float f) {
    unsigned u = __float_as_uint(f);
    unsigned r = u + 0x7FFFu + ((u >> 16) & 1u);   // round-to-nearest-even
    return (unsigned short)(r >> 16);
}
static __device__ __forceinline__ unsigned short f2bf_hw(float f) {
    __hip_bfloat16 h = __float2bfloat16(f);   // HW cvt; pairs fuse to v_cvt_pk_bf16_f32
    return *reinterpret_cast<unsigned short*>(&h);
}

// ---------------------------------------------------------------------------
// Kernel 1: prepack sim_matrix [2048,64] f32 -> bf16 (RTN) MFMA fragments.
// kk-step it (32 k): layout [it(64)][nb(4)][lane(64)][i(8)] shorts (256 KB).
// Content: lane l, elem i -> sim[it*32 + (l>>4)*8 + i][nb*16 + (l&15)]
// B-loads in the main kernel are lane-contiguous 16 B -> fully coalesced.
// Also zero-initializes the fallback counter in d_out.
// ---------------------------------------------------------------------------
__global__ void gating_prepack(const float* __restrict__ sim,
                               unsigned short* __restrict__ Bpk,
                               float* __restrict__ out) {
    int tid = blockIdx.x * 256 + threadIdx.x;
    if (tid == 0) out[FB_OFF] = 0.0f;
    if (tid >= C_DIM * E_DIM) return;
    int k = tid >> 6;
    int e = tid & 63;
    float v = sim[tid];                       // sim[k*64 + e]
    int it = k >> 5;                          // kk-step 0..63
    int gr = (k >> 3) & 3;
    int i  = k & 7;
    int lane = gr * 16 + (e & 15);
    int nb   = e >> 4;
    Bpk[it * 2048 + nb * 512 + lane * 8 + i] = f2bf_rtn(v);
}

// ---------------------------------------------------------------------------
// Kernel 2 (R14 = R10, best measured: 36.4 us): coalesced-A GEMM + epilogue.
// Grid 1024 x 256 (4 waves, 4 blk/CU -> 16 waves/CU). Block = 16 tokens;
// wave w = K-quarter (16 kk-steps), processed as 8 chunks of 2 kk-steps.
// A staged through a wave-private LDS tile with fully-coalesced global loads
// (4 rows x 256 B contiguous per instr), f32->bf16 cvt during staging,
// conflict-free swizzled ds_read_b128 fragment reads (1 per kk-step).
// No barriers in the loop. B register-dbuf from L2 (coalesced).
// ---------------------------------------------------------------------------
__global__ __launch_bounds__(256, 4)
void gating_main(const float* __restrict__ x,
                 const unsigned short* __restrict__ Bpk,
                 const float* __restrict__ gates,
                 float* __restrict__ out) {
    // 4 waves x 2 bufs x 2 KB staging (32 KB), reused as red[4][16][64] after barrier
    __shared__ __align__(16) char smem[32768];

    const int tid = threadIdx.x;
    const int l   = tid & 63;
    const int w   = tid >> 6;          // wave id == K-quarter == C/D reg r
    const int row0 = blockIdx.x * 16;
    const int g    = l >> 4;
    const int e0   = l & 15;

    // staging lane role: instr j covers rows j*4+srow, 16B-unit scol
    const int srow = l >> 4;           // 0..3
    const int scol = l & 15;           // 0..15 (16B units of the 256B row-chunk)

    const float* xq = x + (size_t)row0 * C_DIM + w * 512;
    char* Aw = smem + w * 4096;        // this wave's 2 staging bufs

    // B: per kk-step stride 2048 shorts; lane-contiguous fragment base
    const unsigned short* bw = Bpk + (size_t)w * 16 * 2048 + l * 8;

    f32x4 acc[4];
#pragma unroll
    for (int nb = 0; nb < 4; ++nb) acc[nb] = (f32x4)0.0f;

    // ---- staging helpers -------------------------------------------------
    float4 P[2][4];   // pending load data for 2 chunks
    auto loadA = [&](int ch, int p) {
#pragma unroll
        for (int j = 0; j < 4; ++j) {
            const int row = j * 4 + srow;
            P[p][j] = *(const float4*)(xq + (size_t)row * C_DIM + ch * 64 + scol * 4);
        }
    };
    auto writeA = [&](int p, int b) {
        char* dst = Aw + b * 2048;
#pragma unroll
        for (int j = 0; j < 4; ++j) {
            const int row = j * 4 + srow;
            ushort4 hv;
            hv.x = f2bf_hw(P[p][j].x); hv.y = f2bf_hw(P[p][j].y);
            hv.z = f2bf_hw(P[p][j].z); hv.w = f2bf_hw(P[p][j].w);
            const int wb = (row * 128 + scol * 8) ^ ((row & 7) << 4);
            *(ushort4*)(dst + wb) = hv;
        }
    };
    auto fragA = [&](int it, int b) -> bf16x8 {
        const int rb = (e0 * 128 + (it * 4 + g) * 16) ^ ((e0 & 7) << 4);
        return *(const bf16x8*)(Aw + b * 2048 + rb);
    };

    // ---- prologue --------------------------------------------------------
    loadA(0, 0);
    writeA(0, 0);
    loadA(1, 1);
    bf16x8 Bf[2][4];
#pragma unroll
    for (int b2 = 0; b2 < 2; ++b2)
#pragma unroll
        for (int f = 0; f < 4; ++f)
            Bf[b2][f] = *(const bf16x8*)(bw + b2 * 2048 + f * 512);

    // ---- 8 chunks of 2 kk-steps ------------------------------------------
#pragma unroll
    for (int ch = 0; ch < 8; ++ch) {
        const int b = ch & 1;

        bf16x8 af0 = fragA(0, b);
        bf16x8 af1 = fragA(1, b);

        if (ch < 6) loadA(ch + 2, ch & 1);

#pragma unroll
        for (int it2 = 0; it2 < 2; ++it2) {
            const int itg = ch * 2 + it2;
            const bf16x8 af = it2 ? af1 : af0;
#pragma unroll
            for (int nb = 0; nb < 4; ++nb)
                acc[nb] = __builtin_amdgcn_mfma_f32_16x16x32_bf16(af, Bf[itg & 1][nb], acc[nb], 0, 0, 0);
            if (itg < 14) {
                const unsigned short* bp = bw + (itg + 2) * 2048;
#pragma unroll
                for (int f = 0; f < 4; ++f)
                    Bf[itg & 1][f] = *(const bf16x8*)(bp + f * 512);
            }
        }

        if (ch < 7) writeA((ch + 1) & 1, b ^ 1);
    }

    // ---- cross-wave K reduction (reuse smem after barrier) ----------------
    __syncthreads();
    float (*red)[16][64] = (float(*)[16][64])smem;
#pragma unroll
    for (int nb = 0; nb < 4; ++nb)
#pragma unroll
        for (int r = 0; r < 4; ++r)
            red[w][nb * 4 + r][l] = acc[nb][r];
    __syncthreads();

    float tot[4];
#pragma unroll
    for (int nb = 0; nb < 4; ++nb)
        tot[nb] = red[0][nb * 4 + w][l] + red[1][nb * 4 + w][l]
                + red[2][nb * 4 + w][l] + red[3][nb * 4 + w][l];

    // ---- epilogue: wave w handles tokens t = row0 + g*4 + w ----
    float sig[4];
#pragma unroll
    for (int nb = 0; nb < 4; ++nb)
        sig[nb] = 1.0f / (1.0f + expf(-gates[nb * 16 + e0]));

    const int t = row0 + g * 4 + w;
    float lg[4];
    bool  act[4];
    int   lcnt = 0;
    float lmax = -3.4e38f;
#pragma unroll
    for (int nb = 0; nb < 4; ++nb) {
        lg[nb]  = tot[nb] - sig[nb];
        act[nb] = lg[nb] > 0.0f;
        if (act[nb]) { lcnt++; lmax = fmaxf(lmax, lg[nb]); }
    }
    int cnt = lcnt;
    float mx = lmax;
#pragma unroll
    for (int m = 1; m < 16; m <<= 1) {
        cnt += __shfl_xor(cnt, m, 16);
        mx   = fmaxf(mx, __shfl_xor(mx, m, 16));
    }

    float p[4], am[4];
    if (cnt > 0) {
        float ex[4], ls = 0.0f;
#pragma unroll
        for (int nb = 0; nb < 4; ++nb) {
            ex[nb] = act[nb] ? expf(lg[nb] - mx) : 0.0f;
            ls += ex[nb];
        }
        float Z = ls;
#pragma unroll
        for (int m = 1; m < 16; m <<= 1) Z += __shfl_xor(Z, m, 16);
        float rz = 1.0f / Z;
#pragma unroll
        for (int nb = 0; nb < 4; ++nb) {
            p[nb]  = ex[nb] * rz;
            am[nb] = act[nb] ? 1.0f : 0.0f;
        }
    } else {
        // fallback: top-32 of the 64 logits (ties -> lower expert index).
        // All logits <= 0 here, so probs are uniform 1/32 over the set.
        unsigned selm = 0;
        for (int it = 0; it < 32; ++it) {
            float bv = -3.4e38f;
            int   bi = 127;
#pragma unroll
            for (int nb = 0; nb < 4; ++nb) {
                if (!((selm >> nb) & 1)) {
                    float v = lg[nb];
                    int   e = nb * 16 + e0;
                    if (v > bv || (v == bv && e < bi)) { bv = v; bi = e; }
                }
            }
#pragma unroll
            for (int m = 1; m < 16; m <<= 1) {
                float ov = __shfl_xor(bv, m, 16);
                int   oi = __shfl_xor(bi, m, 16);
                if (ov > bv || (ov == bv && oi < bi)) { bv = ov; bi = oi; }
            }
            if ((bi & 15) == e0) selm |= 1u << (bi >> 4);
        }
#pragma unroll
        for (int nb = 0; nb < 4; ++nb) {
            bool s_ = (selm >> nb) & 1;
            p[nb]  = s_ ? (1.0f / 32.0f) : 0.0f;
            am[nb] = s_ ? 1.0f : 0.0f;
        }
        if (e0 == 0) atomicAdd(&out[FB_OFF], 1.0f);
    }

#pragma unroll
    for (int nb = 0; nb < 4; ++nb) {
        int idx = t * 64 + nb * 16 + e0;
        out[idx]          = p[nb];
        out[LG_OFF + idx] = lg[nb];
        out[AM_OFF + idx] = am[nb];
    }
}

// ---------------------------------------------------------------------------
extern "C" void kernel_launch(void* const* d_in, const int* in_sizes, int n_in,
                              void* d_out, int out_size, void* d_ws, size_t ws_size,
                              hipStream_t stream) {
    const float* x     = (const float*)d_in[0];   // [4,4096,2048] f32
    const float* sim   = (const float*)d_in[1];   // [2048,64] f32
    const float* gates = (const float*)d_in[2];   // [64] f32
    float* out = (float*)d_out;
    unsigned short* Bpk = (unsigned short*)d_ws;  // 256 KB prepacked B (bf16)

    gating_prepack<<<512, 256, 0, stream>>>(sim, Bpk, out);
    gating_main<<<1024, 256, 0, stream>>>(x, Bpk, gates, out);
}